// Round 7
// baseline (482.842 us; speedup 1.0000x reference)
//
#include <hip/hip_runtime.h>

#define MAX_SEQ 2048
#define HEAD_NUM 8

typedef float vfloat4 __attribute__((ext_vector_type(4)));
typedef int   vint4   __attribute__((ext_vector_type(4)));

// Output-linear, constexpr tables (R6 base) + two issue-efficiency changes:
//  (1) f16 round-trip replaced by one exact f32 threshold compare:
//      (half)x > 0.5  <=>  x > 0.5 + 2^-12 (RTNE midpoint, ties-to-even
//      rounds 0.500244140625 down to 0.5). Exact for every f32 input.
//  (2) 4 independent float4-load -> nt-int4-store pairs per thread
//      (4096 output elems per block) for deeper memory-level parallelism.
__global__ __launch_bounds__(256) void genmask_kernel(
    const float* __restrict__ mask,   // (8, 1, 2048, 2048) f32
    int*         __restrict__ out)    // packed int32 0/1 (bool)
{
    // seq_lengths = {2048,1792,1536,1280,1024,768,512,256}
    constexpr unsigned int S[8]  = {2048u,1792u,1536u,1280u,1024u,768u,512u,256u};
    constexpr unsigned int SS[8] = {4194304u,3211264u,2359296u,1638400u,
                                    1048576u,589824u,262144u,65536u};
    // cumulative 4096-elem chunks per batch region (8*ss/4096 each)
    constexpr unsigned int CS[8] = {0u,8192u,14464u,19072u,22272u,
                                    24320u,25472u,25984u};     // total 26112
    // cumulative output element offsets per batch region (8*ss each)
    constexpr unsigned long long ES[8] = {0ull,33554432ull,59244544ull,
        78118912ull,91226112ull,99614720ull,104333312ull,106430464ull};
    // exact magic for rem/s, s=256k: i=(rem*M)>>40, M=floor(2^32/k)+1,
    // exact for rem < 2^22 (max rem = ss-4 <= 2^22-4). absmax=0 in R3-R6.
    constexpr unsigned long long MG[8] = {(1ull<<29)+1, 613566757ull,
        715827883ull, 858993460ull, (1ull<<30)+1, 1431655766ull,
        (1ull<<31)+1, (1ull<<32)+1};

    const unsigned int blk = blockIdx.x;

    // Branchless batch lookup on immediates (wave-uniform).
    int b = 0;
    #pragma unroll
    for (int t = 1; t < 8; ++t) b += (blk >= CS[t]) ? 1 : 0;

    const unsigned int s  = S[b];
    const unsigned int ss = SS[b];
    const unsigned long long M = MG[b];

    // Element base within this batch's output region [0, 8*ss).
    const unsigned int base = (blk - CS[b]) * 4096u;
    // base mod ss (uniform; ss is a multiple of 4096 -> chunk is one head).
    unsigned int rem_base = base;
    #pragma unroll
    for (int t = 0; t < HEAD_NUM - 1; ++t)
        if (rem_base >= ss) rem_base -= ss;

    const float* in_b  = mask + (size_t)b * MAX_SEQ * MAX_SEQ;
    int*         out_p = out + ES[b] + base;
    const unsigned int t4 = threadIdx.x * 4u;

    // (half)x > 0.5  <=>  x > 0.5 + 2^-12  (exact, see header comment)
    constexpr float TH = 0.500244140625f;

    // 4 independent load/convert/store pairs.
    vfloat4 v[4];
    #pragma unroll
    for (int c = 0; c < 4; ++c) {
        const unsigned int rem = rem_base + c * 1024u + t4;
        const unsigned int i = (unsigned int)(((unsigned long long)rem * M) >> 40);
        const unsigned int j = rem - i * s;
        v[c] = *(const vfloat4*)(in_b + (size_t)i * MAX_SEQ + j);
    }
    #pragma unroll
    for (int c = 0; c < 4; ++c) {
        vint4 r;
        r.x = (v[c].x > TH) ? 1 : 0;
        r.y = (v[c].y > TH) ? 1 : 0;
        r.z = (v[c].z > TH) ? 1 : 0;
        r.w = (v[c].w > TH) ? 1 : 0;
        __builtin_nontemporal_store(r, (vint4*)(out_p + c * 1024u + t4));
    }
}

extern "C" void kernel_launch(void* const* d_in, const int* in_sizes, int n_in,
                              void* d_out, int out_size, void* d_ws, size_t ws_size,
                              hipStream_t stream) {
    const float* mask = (const float*)d_in[0];
    int*         out  = (int*)d_out;

    const unsigned int n_blocks = (unsigned int)(out_size / 4096);  // 26112

    genmask_kernel<<<n_blocks, 256, 0, stream>>>(mask, out);
}